// Round 1
// baseline (207.825 us; speedup 1.0000x reference)
//
#include <hip/hip_runtime.h>

// B=16, V=20000, D=256, H=256. Output fp32 (16*20000).
// Pipeline: prep (repack weights to MFMA frag order + patient path)
//        -> atc4_fused (bf16 MFMA GEMM1 + rowLN + GEMM2, transposed store)
//        -> scores (tanh contraction, partial over 8 h-chunks)
//        -> final_ln (reduce partials + LN over V)

typedef unsigned short ushort_t;
typedef __attribute__((ext_vector_type(8))) short short8;
typedef __attribute__((ext_vector_type(4))) float floatx4;

#define C2F 2.8853900817779268f  // 2*log2(e): exp(2x) = exp2(C2F*x)
#define V_N 20000

__device__ __forceinline__ ushort_t f2bf(float f) {
    unsigned int u = __builtin_bit_cast(unsigned int, f);
    u += 0x7FFFu + ((u >> 16) & 1u);   // round-to-nearest-even
    return (ushort_t)(u >> 16);
}

// ---------------------------------------------------------------------------
// prep: blocks 0..15 repack Wa and W1[D:] (fp32->bf16, MFMA B-fragment order);
//       blocks 16..31 compute php[b][h] = C2F * (LN(pe@Wp+bp)@W1[:D])[b][h]
// Fragment order: slot = (kstep*16 + ntile)*64 + lane, 8 contiguous bf16 per
// lane = B[kstep*32 + (lane>>4)*8 + j][ntile*16 + (lane&15)], j=0..7.
// ---------------------------------------------------------------------------
__global__ __launch_bounds__(1024) void prep_kernel(
    const float* __restrict__ patient_emb, const float* __restrict__ Wp,
    const float* __restrict__ bp, const float* __restrict__ gp,
    const float* __restrict__ betap,
    const float* __restrict__ Wa, const float* __restrict__ W1,
    ushort_t* __restrict__ pWa, ushort_t* __restrict__ pW1b,
    float* __restrict__ php)
{
    const int blk = blockIdx.x;
    const int tid = threadIdx.x;
    __shared__ float peL[256];
    __shared__ float pL[256];
    __shared__ float part[4][256];
    __shared__ float red[8];

    if (blk < 16) {
        // 16 blocks * 1024 threads = 16384 slots = 2 matrices * 8192
        int slot = blk * 1024 + tid;
        int matrix = slot >> 13;
        int rest = slot & 8191;
        int s = rest >> 10;
        int T = (rest >> 6) & 15;
        int l = rest & 63;
        const float* src = matrix ? (W1 + 256 * 256) : Wa;  // W1 rows 256..511
        ushort_t* dst = matrix ? pW1b : pWa;
        int kbase = s * 32 + ((l >> 4) << 3);
        int nn = (T << 4) + (l & 15);
        #pragma unroll
        for (int j = 0; j < 8; ++j)
            dst[rest * 8 + j] = f2bf(src[(kbase + j) * 256 + nn]);
        return;
    }

    // ---- patient path: one block (1024 thr) per batch row ----
    const int b = blk - 16;
    const int j = tid & 255, pq = tid >> 8;   // 4-way split of the K dim
    if (tid < 256) peL[tid] = patient_emb[b * 256 + tid];
    __syncthreads();
    float a0 = 0.f;
    #pragma unroll 8
    for (int dd = 0; dd < 64; ++dd) {
        int d = pq * 64 + dd;
        a0 += peL[d] * Wp[d * 256 + j];
    }
    part[pq][j] = a0;
    __syncthreads();
    float x = 0.f;
    if (tid < 256) {
        x = part[0][j] + part[1][j] + part[2][j] + part[3][j] + bp[j];
        float s1 = x, s2 = x * x;
        #pragma unroll
        for (int off = 32; off; off >>= 1) {
            s1 += __shfl_xor(s1, off);
            s2 += __shfl_xor(s2, off);
        }
        int wv = tid >> 6;
        if ((tid & 63) == 0) { red[wv * 2] = s1; red[wv * 2 + 1] = s2; }
    }
    __syncthreads();
    if (tid < 256) {
        float s1 = red[0] + red[2] + red[4] + red[6];
        float s2 = red[1] + red[3] + red[5] + red[7];
        float mean = s1 * (1.f / 256.f);
        float var  = s2 * (1.f / 256.f) - mean * mean;
        float rstd = rsqrtf(var + 1e-5f);
        pL[tid] = (x - mean) * rstd * gp[tid] + betap[tid];
    }
    __syncthreads();
    float a2 = 0.f;
    #pragma unroll 8
    for (int dd = 0; dd < 64; ++dd) {
        int d = pq * 64 + dd;
        a2 += pL[d] * W1[d * 256 + j];   // W1[:D]
    }
    part[pq][j] = a2;
    __syncthreads();
    if (tid < 256)
        php[b * 256 + tid] = C2F * (part[0][tid] + part[1][tid] + part[2][tid] + part[3][tid]);
}

// ---------------------------------------------------------------------------
// atc4_fused: per block, 64 rows of V. GEMM1 (atc4@Wa, bf16 MFMA 16x16x32)
// + bias + row-LN -> bf16 A-tile in LDS -> GEMM2 (@W1[D:]) -> epilogue
// writes ahT[h][v] = C2F*(ah+b1) transposed via per-wave LDS buffers.
// Wave w owns cols [64w,64w+64) as 4 n-tiles; 4 m-tiles of 16 rows each.
// MFMA 16x16x32_bf16 layouts (guide-verified A, C/D; B mirrored):
//   A: lane holds A[m=lane&15][k=(lane>>4)*8+j]   (8 bf16, ds_read_b128)
//   C/D: D[(lane>>4)*4+reg][lane&15]
// ---------------------------------------------------------------------------
__global__ __launch_bounds__(256) void atc4_fused(
    const float* __restrict__ atc4,
    const float* __restrict__ ba, const float* __restrict__ ga,
    const float* __restrict__ betaa, const float* __restrict__ b1,
    const ushort_t* __restrict__ pWa, const ushort_t* __restrict__ pW1b,
    float* __restrict__ ahT)
{
    __shared__ ushort_t Atile[64][264];     // 256 + 8 pad -> 528B row, 16B-aligned
    __shared__ float stats[4][64][2];       // [wave][row][{sum,sumsq}]
    __shared__ float xpose[4][16][65];      // per-wave transpose buffer

    const int tid = threadIdx.x;
    const int w = tid >> 6, l = tid & 63;
    const int q = l >> 4, n = l & 15;
    const int v0 = blockIdx.x * 64;

    // ---- stage A tile (fp32 -> bf16), zero-pad rows >= V ----
    #pragma unroll
    for (int i = 0; i < 16; ++i) {
        int idx = i * 256 + tid;
        int row = idx >> 6, c4 = idx & 63;
        float4 f = make_float4(0.f, 0.f, 0.f, 0.f);
        if (v0 + row < V_N) f = *(const float4*)(atc4 + (v0 + row) * 256 + c4 * 4);
        ushort4 us = make_ushort4(f2bf(f.x), f2bf(f.y), f2bf(f.z), f2bf(f.w));
        *(ushort4*)(&Atile[row][c4 * 4]) = us;
    }
    __syncthreads();

    const floatx4 zero4 = {0.f, 0.f, 0.f, 0.f};
    floatx4 acc[4][4];
    #pragma unroll
    for (int mi = 0; mi < 4; ++mi)
        #pragma unroll
        for (int ni = 0; ni < 4; ++ni) acc[mi][ni] = zero4;

    // ---- GEMM1 K-loop ----
    #pragma unroll
    for (int s = 0; s < 8; ++s) {
        short8 af[4], bf[4];
        #pragma unroll
        for (int mi = 0; mi < 4; ++mi)
            af[mi] = *(const short8*)(&Atile[mi * 16 + n][s * 32 + q * 8]);
        #pragma unroll
        for (int ni = 0; ni < 4; ++ni)
            bf[ni] = *(const short8*)(pWa + ((s * 16 + (w * 4 + ni)) * 64 + l) * 8);
        #pragma unroll
        for (int mi = 0; mi < 4; ++mi)
            #pragma unroll
            for (int ni = 0; ni < 4; ++ni)
                acc[mi][ni] = __builtin_amdgcn_mfma_f32_16x16x32_bf16(
                    af[mi], bf[ni], acc[mi][ni], 0, 0, 0);
    }

    // ---- epilogue 1: +bias, row-LN across 256 cols, bf16 back into Atile ----
    float bac[4], gac[4], bec[4], b1c[4];
    #pragma unroll
    for (int ni = 0; ni < 4; ++ni) {
        int col = w * 64 + ni * 16 + n;
        bac[ni] = ba[col]; gac[ni] = ga[col]; bec[ni] = betaa[col]; b1c[ni] = b1[col];
    }
    float s1[4][4], s2[4][4];
    #pragma unroll
    for (int mi = 0; mi < 4; ++mi)
        #pragma unroll
        for (int r = 0; r < 4; ++r) {
            float t1 = 0.f, t2 = 0.f;
            #pragma unroll
            for (int ni = 0; ni < 4; ++ni) {
                float xv = acc[mi][ni][r] + bac[ni];
                acc[mi][ni][r] = xv;
                t1 += xv; t2 += xv * xv;
            }
            s1[mi][r] = t1; s2[mi][r] = t2;
        }
    #pragma unroll
    for (int off = 1; off < 16; off <<= 1) {   // reduce over the 16 n-lanes
        #pragma unroll
        for (int mi = 0; mi < 4; ++mi)
            #pragma unroll
            for (int r = 0; r < 4; ++r) {
                s1[mi][r] += __shfl_xor(s1[mi][r], off);
                s2[mi][r] += __shfl_xor(s2[mi][r], off);
            }
    }
    if (n == 0) {
        #pragma unroll
        for (int mi = 0; mi < 4; ++mi)
            #pragma unroll
            for (int r = 0; r < 4; ++r) {
                int row = mi * 16 + q * 4 + r;
                stats[w][row][0] = s1[mi][r];
                stats[w][row][1] = s2[mi][r];
            }
    }
    __syncthreads();  // also guarantees all waves finished reading Atile (GEMM1)
    #pragma unroll
    for (int mi = 0; mi < 4; ++mi)
        #pragma unroll
        for (int r = 0; r < 4; ++r) {
            int row = mi * 16 + q * 4 + r;
            float m1 = stats[0][row][0] + stats[1][row][0] + stats[2][row][0] + stats[3][row][0];
            float m2 = stats[0][row][1] + stats[1][row][1] + stats[2][row][1] + stats[3][row][1];
            float mean = m1 * (1.f / 256.f);
            float var  = m2 * (1.f / 256.f) - mean * mean;
            float rstd = rsqrtf(var + 1e-5f);
            #pragma unroll
            for (int ni = 0; ni < 4; ++ni) {
                float xv = (acc[mi][ni][r] - mean) * rstd * gac[ni] + bec[ni];
                Atile[row][w * 64 + ni * 16 + n] = f2bf(xv);
            }
        }
    __syncthreads();

    // ---- GEMM2 K-loop (A = LN'd a-tile in LDS, B = packed W1[D:]) ----
    floatx4 acc2[4][4];
    #pragma unroll
    for (int mi = 0; mi < 4; ++mi)
        #pragma unroll
        for (int ni = 0; ni < 4; ++ni) acc2[mi][ni] = zero4;
    #pragma unroll
    for (int s = 0; s < 8; ++s) {
        short8 af[4], bf[4];
        #pragma unroll
        for (int mi = 0; mi < 4; ++mi)
            af[mi] = *(const short8*)(&Atile[mi * 16 + n][s * 32 + q * 8]);
        #pragma unroll
        for (int ni = 0; ni < 4; ++ni)
            bf[ni] = *(const short8*)(pW1b + ((s * 16 + (w * 4 + ni)) * 64 + l) * 8);
        #pragma unroll
        for (int mi = 0; mi < 4; ++mi)
            #pragma unroll
            for (int ni = 0; ni < 4; ++ni)
                acc2[mi][ni] = __builtin_amdgcn_mfma_f32_16x16x32_bf16(
                    af[mi], bf[ni], acc2[mi][ni], 0, 0, 0);
    }

    // ---- epilogue 2: scale, transpose per wave via LDS, coalesced store ----
    #pragma unroll
    for (int ni = 0; ni < 4; ++ni) {
        __syncthreads();
        #pragma unroll
        for (int mi = 0; mi < 4; ++mi)
            #pragma unroll
            for (int r = 0; r < 4; ++r)
                xpose[w][n][mi * 16 + q * 4 + r] = (acc2[mi][ni][r] + b1c[ni]) * C2F;
        __syncthreads();
        #pragma unroll
        for (int hh = 0; hh < 16; ++hh) {
            int h = w * 64 + ni * 16 + hh;
            int v = v0 + l;
            if (v < V_N) ahT[h * V_N + v] = xpose[w][hh][l];
        }
    }
}

// ---------------------------------------------------------------------------
// scores: partial[hc][b][v] = sum_{h in chunk} W2[h] / (exp2(php+ahs)+1)
// tanh identity: sum W2*tanh = (const) - 2*sum W2/(u+1); const cancels in LN.
// ---------------------------------------------------------------------------
__global__ __launch_bounds__(256) void scores_kernel(
    const float* __restrict__ ahT, const float* __restrict__ php,
    const float* __restrict__ W2, float* __restrict__ partials)
{
    __shared__ float phL[512];   // [b][32] for this h-chunk
    __shared__ float w2L[32];
    const int tid = threadIdx.x;
    const int hc = blockIdx.y;       // 0..7
    const int v = blockIdx.x * 256 + tid;
    {
        int i = tid;
        phL[i] = php[(i >> 5) * 256 + hc * 32 + (i & 31)];
        i = tid + 256;
        phL[i] = php[(i >> 5) * 256 + hc * 32 + (i & 31)];
        if (tid < 32) w2L[tid] = W2[hc * 32 + tid];
    }
    __syncthreads();
    float acc[16];
    #pragma unroll
    for (int b = 0; b < 16; ++b) acc[b] = 0.f;
    #pragma unroll 2
    for (int jj = 0; jj < 32; ++jj) {
        float a = ahT[(hc * 32 + jj) * V_N + v];   // coalesced; OOB v reads scratch, discarded
        float w2 = w2L[jj];
        #pragma unroll
        for (int b = 0; b < 16; ++b) {
            float u = __builtin_amdgcn_exp2f(phL[b * 32 + jj] + a);
            acc[b] += w2 * __builtin_amdgcn_rcpf(u + 1.f);
        }
    }
    if (v < V_N) {
        #pragma unroll
        for (int b = 0; b < 16; ++b)
            partials[(hc * 16 + b) * V_N + v] = acc[b];
    }
}

// ---------------------------------------------------------------------------
// final_ln: raw = -2 * sum_c partial; LN over V per batch row (shift-invariant
// so dropped b2+sum(W2) constant is harmless), apply g_pred/b_pred.
// ---------------------------------------------------------------------------
__global__ __launch_bounds__(1024) void final_ln(
    const float* __restrict__ partials, const float* __restrict__ g_pred,
    const float* __restrict__ b_pred, float* __restrict__ out)
{
    __shared__ float red[32];
    const int b = blockIdx.x, tid = threadIdx.x;
    float rawv[20];
    float s1 = 0.f, ssq = 0.f;
    #pragma unroll
    for (int it = 0; it < 20; ++it) {
        int v = tid + it * 1024;
        float raw = 0.f;
        if (v < V_N) {
            float P = 0.f;
            #pragma unroll
            for (int c = 0; c < 8; ++c) P += partials[(c * 16 + b) * V_N + v];
            raw = -2.f * P;
            s1 += raw; ssq += raw * raw;
        }
        rawv[it] = raw;
    }
    #pragma unroll
    for (int off = 32; off; off >>= 1) {
        s1 += __shfl_xor(s1, off);
        ssq += __shfl_xor(ssq, off);
    }
    int wv = tid >> 6;
    if ((tid & 63) == 0) { red[wv] = s1; red[16 + wv] = ssq; }
    __syncthreads();
    float t1 = 0.f, t2 = 0.f;
    #pragma unroll
    for (int i = 0; i < 16; ++i) { t1 += red[i]; t2 += red[16 + i]; }
    float mean = t1 * (1.f / 20000.f);
    float var  = t2 * (1.f / 20000.f) - mean * mean;
    float rstd = rsqrtf(var + 1e-5f);
    #pragma unroll
    for (int it = 0; it < 20; ++it) {
        int v = tid + it * 1024;
        if (v < V_N)
            out[b * V_N + v] = (rawv[it] - mean) * rstd * g_pred[v] + b_pred[v];
    }
}

extern "C" void kernel_launch(void* const* d_in, const int* in_sizes, int n_in,
                              void* d_out, int out_size, void* d_ws, size_t ws_size,
                              hipStream_t stream)
{
    const float* patient_emb = (const float*)d_in[0];
    const float* atc4        = (const float*)d_in[1];
    const float* Wp    = (const float*)d_in[2];
    const float* bp    = (const float*)d_in[3];
    const float* gp    = (const float*)d_in[4];
    const float* betap = (const float*)d_in[5];
    const float* Wa    = (const float*)d_in[6];
    const float* ba    = (const float*)d_in[7];
    const float* ga    = (const float*)d_in[8];
    const float* betaa = (const float*)d_in[9];
    const float* W1    = (const float*)d_in[10];
    const float* b1    = (const float*)d_in[11];
    const float* W2    = (const float*)d_in[12];
    // d_in[13] = b2: constant offset, cancels under the final LN
    const float* g_pred = (const float*)d_in[14];
    const float* b_pred = (const float*)d_in[15];

    char* ws = (char*)d_ws;
    float*    php      = (float*)(ws);               // 16 KB
    ushort_t* pWa      = (ushort_t*)(ws + (1 << 16)); // 128 KB
    ushort_t* pW1b     = (ushort_t*)(ws + (1 << 18)); // 128 KB
    float*    ahT      = (float*)(ws + (1 << 20));    // 256*20000*4 = 20.48 MB
    float*    partials = (float*)(ws + 22020096);     // 8*16*20000*4 = 10.24 MB
    float*    out      = (float*)d_out;

    prep_kernel<<<32, 1024, 0, stream>>>(patient_emb, Wp, bp, gp, betap,
                                         Wa, W1, pWa, pW1b, php);
    atc4_fused<<<313, 256, 0, stream>>>(atc4, ba, ga, betaa, b1, pWa, pW1b, ahT);
    scores_kernel<<<dim3(79, 8), 256, 0, stream>>>(ahT, php, W2, partials);
    final_ln<<<16, 1024, 0, stream>>>(partials, g_pred, b_pred, out);
}